// Round 1
// baseline (370.770 us; speedup 1.0000x reference)
//
#include <hip/hip_runtime.h>

#define NNODES 50000
#define DIN 128
#define DHID 128
#define DOUT 128
#define NEG_SLOPE 0.01f

typedef _Float16 f16x8 __attribute__((ext_vector_type(8)));
typedef _Float16 f16x4 __attribute__((ext_vector_type(4)));
typedef float f32x4 __attribute__((ext_vector_type(4)));

// d_ws layout (halves):
//  WqB hi: [ct(8)][g(4)][l(64)][8]   = 16384 halves
//  WqB lo: 16384
//  WwB hi: [ct(8)][g(8)][l(64)][8]   = 32768 halves
//  WwB lo: 32768
#define WS_WQ_HI 0
#define WS_WQ_LO 16384
#define WS_WW_HI 32768
#define WS_WW_LO 65536

// ---------------------------------------------------------------- kernel 0
// Convert weights to fp16 hi/lo fragment slabs.
// Fragment convention (mfma_f32_16x16x32_f16):
//   A: row = l&15, k = (l>>4)*8 + j
//   B: col = l&15, k = (l>>4)*8 + j
//   D: col = l&15, row = (l>>4)*4 + r
__global__ void convert_weights(const float* __restrict__ Wq,
                                const float* __restrict__ Ww,
                                _Float16* __restrict__ ws) {
    int id = blockIdx.x * 256 + threadIdx.x;
    if (id < 2048) {  // Wq slots: B[k][col] = Wq[col][k]
        int s  = id;
        int l  = s & 63;
        int g  = (s >> 6) & 3;
        int ct = s >> 8;
        int col = ct * 16 + (l & 15);
        int k0  = g * 32 + (l >> 4) * 8;
        const float* src = Wq + col * DIN + k0;
        f16x8 vh, vl;
#pragma unroll
        for (int j = 0; j < 8; ++j) {
            float v = src[j];
            _Float16 h = (_Float16)v;
            vh[j] = h;
            vl[j] = (_Float16)(v - (float)h);
        }
        *(f16x8*)(ws + WS_WQ_HI + s * 8) = vh;
        *(f16x8*)(ws + WS_WQ_LO + s * 8) = vl;
    } else if (id < 2048 + 4096) {  // Ww slots: B2[k][o] = Ww[o][k]
        int s  = id - 2048;
        int l  = s & 63;
        int g  = (s >> 6) & 7;
        int ct = s >> 9;
        int col = ct * 16 + (l & 15);
        int k0  = g * 32 + (l >> 4) * 8;
        const float* src = Ww + col * (DIN + DHID) + k0;
        f16x8 vh, vl;
#pragma unroll
        for (int j = 0; j < 8; ++j) {
            float v = src[j];
            _Float16 h = (_Float16)v;
            vh[j] = h;
            vl[j] = (_Float16)(v - (float)h);
        }
        *(f16x8*)(ws + WS_WW_HI + s * 8) = vh;
        *(f16x8*)(ws + WS_WW_LO + s * 8) = vl;
    }
}

// ---------------------------------------------------------------- kernel 1
// GEMM1 (rows = node*32+k_n) + leaky + alpha-weighted mean -> hagg (= d_out)
// Tile: 128 rows x 128 cols, K=128 in 4 chunks of BK=32.
// 4 waves in 2x2; wave tile 64x64.
__global__ __launch_bounds__(256, 2) void gemm1_agg(
    const float* __restrict__ hng,    // [NNODES*32][128]
    const float* __restrict__ alpha,  // [NNODES*32]
    const float* __restrict__ bq,     // [128]
    const _Float16* __restrict__ ws,
    float* __restrict__ hagg)         // [NNODES][128]
{
    __shared__ _Float16 Ahi[8 * 520];  // 8 slabs, stride 520 halves (pad 8)
    __shared__ _Float16 Alo[8 * 520];
    __shared__ _Float16 Bhi[8 * 512];
    __shared__ _Float16 Blo[8 * 512];
    __shared__ float alpha_s[128];
    __shared__ float bq_s[128];

    const int tid = threadIdx.x;
    const int l   = tid & 63;
    const int wid = tid >> 6;
    const int wr  = wid >> 1, wc = wid & 1;
    const long R0 = (long)blockIdx.x * 128;

    if (tid < 128) {
        alpha_s[tid] = alpha[R0 + tid];
        bq_s[tid]    = bq[tid];
    }

    f32x4 acc[4][4];
#pragma unroll
    for (int i = 0; i < 4; ++i)
#pragma unroll
        for (int j = 0; j < 4; ++j) acc[i][j] = (f32x4){0.f, 0.f, 0.f, 0.f};

    const _Float16* wqh = ws + WS_WQ_HI;
    const _Float16* wql = ws + WS_WQ_LO;

    for (int c = 0; c < 4; ++c) {
        __syncthreads();
        // ---- stage A: 128 rows x 32 k, convert fp32 -> f16 hi/lo, frag order
#pragma unroll
        for (int p = 0; p < 4; ++p) {
            int row = p * 32 + (tid >> 3);
            int kk  = (tid & 7) * 4;  // within-chunk k
            const float* g = hng + (R0 + row) * DIN + c * 32 + kk;
            float4 v = *(const float4*)g;
            _Float16 h0 = (_Float16)v.x, h1 = (_Float16)v.y;
            _Float16 h2 = (_Float16)v.z, h3 = (_Float16)v.w;
            f16x4 vh = {h0, h1, h2, h3};
            f16x4 vl = {(_Float16)(v.x - (float)h0), (_Float16)(v.y - (float)h1),
                        (_Float16)(v.z - (float)h2), (_Float16)(v.w - (float)h3)};
            int lw  = (row & 15) | (((kk >> 3) & 3) << 4);
            int s   = row >> 4;
            int off = s * 520 + lw * 8 + (kk & 7);
            *(f16x4*)(Ahi + off) = vh;
            *(f16x4*)(Alo + off) = vl;
        }
        // ---- stage B: copy pre-converted slabs (g = c), 16 slabs of 1KB
#pragma unroll
        for (int i = 0; i < 4; ++i) {
            int id = i * 256 + tid;
            int sb = id >> 6;  // 0..15
            int ls = id & 63;
            if (sb < 8) {
                *(f16x8*)(Bhi + sb * 512 + ls * 8) =
                    *(const f16x8*)(wqh + ((sb * 4 + c) * 64 + ls) * 8);
            } else {
                int ct = sb - 8;
                *(f16x8*)(Blo + ct * 512 + ls * 8) =
                    *(const f16x8*)(wql + ((ct * 4 + c) * 64 + ls) * 8);
            }
        }
        __syncthreads();
        // ---- compute: 16 ds_read_b128 + 48 MFMA per wave
        f16x8 ah[4], al[4], bh[4], bl[4];
#pragma unroll
        for (int rt = 0; rt < 4; ++rt) {
            int s = wr * 4 + rt;
            ah[rt] = *(const f16x8*)(Ahi + s * 520 + l * 8);
            al[rt] = *(const f16x8*)(Alo + s * 520 + l * 8);
        }
#pragma unroll
        for (int ct = 0; ct < 4; ++ct) {
            int s = wc * 4 + ct;
            bh[ct] = *(const f16x8*)(Bhi + s * 512 + l * 8);
            bl[ct] = *(const f16x8*)(Blo + s * 512 + l * 8);
        }
#pragma unroll
        for (int rt = 0; rt < 4; ++rt)
#pragma unroll
            for (int ct = 0; ct < 4; ++ct) {
                acc[rt][ct] = __builtin_amdgcn_mfma_f32_16x16x32_f16(ah[rt], bh[ct], acc[rt][ct], 0, 0, 0);
                acc[rt][ct] = __builtin_amdgcn_mfma_f32_16x16x32_f16(ah[rt], bl[ct], acc[rt][ct], 0, 0, 0);
                acc[rt][ct] = __builtin_amdgcn_mfma_f32_16x16x32_f16(al[rt], bh[ct], acc[rt][ct], 0, 0, 0);
            }
    }

    // ---- epilogue: +bq, leaky, *alpha, reduce 32 rows/node, safediv, store
    const int grp = l >> 4;
    float part[2][4] = {{0.f, 0.f, 0.f, 0.f}, {0.f, 0.f, 0.f, 0.f}};
    float apart[2] = {0.f, 0.f};
#pragma unroll
    for (int rt = 0; rt < 4; ++rt) {
        const int nl = rt >> 1;
#pragma unroll
        for (int r = 0; r < 4; ++r) {
            int rowl = wr * 64 + rt * 16 + grp * 4 + r;
            float aw = alpha_s[rowl];
            apart[nl] += aw;
#pragma unroll
            for (int ct = 0; ct < 4; ++ct) {
                int col = wc * 64 + ct * 16 + (l & 15);
                float v = acc[rt][ct][r] + bq_s[col];
                v = (v >= 0.f) ? v : NEG_SLOPE * v;
                part[nl][ct] += aw * v;
            }
        }
    }
#pragma unroll
    for (int nl = 0; nl < 2; ++nl) {
        apart[nl] += __shfl_xor(apart[nl], 16);
        apart[nl] += __shfl_xor(apart[nl], 32);
#pragma unroll
        for (int ct = 0; ct < 4; ++ct) {
            part[nl][ct] += __shfl_xor(part[nl][ct], 16);
            part[nl][ct] += __shfl_xor(part[nl][ct], 32);
        }
    }
    if (grp < 2) {  // lanes 0..15 -> node0, 16..31 -> node1 (of this wave's pair)
        int nl = grp;
        long node = (long)blockIdx.x * 4 + wr * 2 + nl;
        float den = apart[nl];
        if (den == 0.f) den = 1.f;
#pragma unroll
        for (int ct = 0; ct < 4; ++ct) {
            int col = wc * 64 + ct * 16 + (l & 15);
            hagg[node * DHID + col] = part[nl][ct] / den;
        }
    }
}

// ---------------------------------------------------------------- kernel 2
// GEMM2: out = normalize(leaky(concat(h_node, hagg) @ Ww^T + bw))
// Tile: 128 nodes x 128 out, K=256 in 8 chunks of 32. hagg lives in `out`.
__global__ __launch_bounds__(256, 2) void gemm2_norm(
    const float* __restrict__ hnode,  // [NNODES][128]
    const float* __restrict__ bw,     // [128]
    const _Float16* __restrict__ ws,
    float* __restrict__ out)          // [NNODES][128], holds hagg on entry
{
    __shared__ _Float16 Ahi[8 * 520];
    __shared__ _Float16 Alo[8 * 520];
    __shared__ _Float16 Bhi[8 * 512];
    __shared__ _Float16 Blo[8 * 512];
    __shared__ float bw_s[128];
    __shared__ float nbuf[2][128];

    const int tid = threadIdx.x;
    const int l   = tid & 63;
    const int wid = tid >> 6;
    const int wr  = wid >> 1, wc = wid & 1;
    const long NB = (long)blockIdx.x * 128;

    if (tid < 128) bw_s[tid] = bw[tid];

    f32x4 acc[4][4];
#pragma unroll
    for (int i = 0; i < 4; ++i)
#pragma unroll
        for (int j = 0; j < 4; ++j) acc[i][j] = (f32x4){0.f, 0.f, 0.f, 0.f};

    const _Float16* wwh = ws + WS_WW_HI;
    const _Float16* wwl = ws + WS_WW_LO;

    for (int c = 0; c < 8; ++c) {
        __syncthreads();
        // ---- stage A: 128 nodes x 32 k of concat(h_node, hagg)
#pragma unroll
        for (int p = 0; p < 4; ++p) {
            int rl = p * 32 + (tid >> 3);
            long n = NB + rl;
            if (n > NNODES - 1) n = NNODES - 1;  // tail clamp (stores guarded)
            int kw = (tid & 7) * 4;       // within-chunk k
            int kg = c * 32 + kw;         // global k in 0..255
            const float* g = (kg < 128) ? (hnode + n * DIN + kg)
                                        : (out + n * DHID + (kg - 128));
            float4 v = *(const float4*)g;
            _Float16 h0 = (_Float16)v.x, h1 = (_Float16)v.y;
            _Float16 h2 = (_Float16)v.z, h3 = (_Float16)v.w;
            f16x4 vh = {h0, h1, h2, h3};
            f16x4 vl = {(_Float16)(v.x - (float)h0), (_Float16)(v.y - (float)h1),
                        (_Float16)(v.z - (float)h2), (_Float16)(v.w - (float)h3)};
            int lw  = (rl & 15) | (((kw >> 3) & 3) << 4);
            int s   = rl >> 4;
            int off = s * 520 + lw * 8 + (kw & 7);
            *(f16x4*)(Ahi + off) = vh;
            *(f16x4*)(Alo + off) = vl;
        }
        // ---- stage B slabs (g = c)
#pragma unroll
        for (int i = 0; i < 4; ++i) {
            int id = i * 256 + tid;
            int sb = id >> 6;
            int ls = id & 63;
            if (sb < 8) {
                *(f16x8*)(Bhi + sb * 512 + ls * 8) =
                    *(const f16x8*)(wwh + ((sb * 8 + c) * 64 + ls) * 8);
            } else {
                int ct = sb - 8;
                *(f16x8*)(Blo + ct * 512 + ls * 8) =
                    *(const f16x8*)(wwl + ((ct * 8 + c) * 64 + ls) * 8);
            }
        }
        __syncthreads();
        // ---- compute
        f16x8 ah[4], al[4], bh[4], bl[4];
#pragma unroll
        for (int rt = 0; rt < 4; ++rt) {
            int s = wr * 4 + rt;
            ah[rt] = *(const f16x8*)(Ahi + s * 520 + l * 8);
            al[rt] = *(const f16x8*)(Alo + s * 520 + l * 8);
        }
#pragma unroll
        for (int ct = 0; ct < 4; ++ct) {
            int s = wc * 4 + ct;
            bh[ct] = *(const f16x8*)(Bhi + s * 512 + l * 8);
            bl[ct] = *(const f16x8*)(Blo + s * 512 + l * 8);
        }
#pragma unroll
        for (int rt = 0; rt < 4; ++rt)
#pragma unroll
            for (int ct = 0; ct < 4; ++ct) {
                acc[rt][ct] = __builtin_amdgcn_mfma_f32_16x16x32_f16(ah[rt], bh[ct], acc[rt][ct], 0, 0, 0);
                acc[rt][ct] = __builtin_amdgcn_mfma_f32_16x16x32_f16(ah[rt], bl[ct], acc[rt][ct], 0, 0, 0);
                acc[rt][ct] = __builtin_amdgcn_mfma_f32_16x16x32_f16(al[rt], bh[ct], acc[rt][ct], 0, 0, 0);
            }
    }

    // ---- epilogue: +bw, leaky, row L2-norm (128 cols), safediv, store
    const int grp = l >> 4;
#pragma unroll
    for (int rt = 0; rt < 4; ++rt)
#pragma unroll
        for (int ct = 0; ct < 4; ++ct)
#pragma unroll
            for (int r = 0; r < 4; ++r) {
                int col = wc * 64 + ct * 16 + (l & 15);
                float v = acc[rt][ct][r] + bw_s[col];
                acc[rt][ct][r] = (v >= 0.f) ? v : NEG_SLOPE * v;
            }
    float ssq[4][4];
#pragma unroll
    for (int rt = 0; rt < 4; ++rt)
#pragma unroll
        for (int r = 0; r < 4; ++r) {
            float s = 0.f;
#pragma unroll
            for (int ct = 0; ct < 4; ++ct) s += acc[rt][ct][r] * acc[rt][ct][r];
            s += __shfl_xor(s, 1);
            s += __shfl_xor(s, 2);
            s += __shfl_xor(s, 4);
            s += __shfl_xor(s, 8);
            ssq[rt][r] = s;  // sum over this wave's 64 cols, row rt*16+grp*4+r
        }
    if ((l & 15) == 0) {
#pragma unroll
        for (int rt = 0; rt < 4; ++rt)
#pragma unroll
            for (int r = 0; r < 4; ++r)
                nbuf[wc][wr * 64 + rt * 16 + grp * 4 + r] = ssq[rt][r];
    }
    __syncthreads();
#pragma unroll
    for (int rt = 0; rt < 4; ++rt)
#pragma unroll
        for (int r = 0; r < 4; ++r) {
            int rowl = wr * 64 + rt * 16 + grp * 4 + r;
            long n = NB + rowl;
            if (n < NNODES) {
                float nrm = sqrtf(nbuf[0][rowl] + nbuf[1][rowl]);
                if (nrm == 0.f) nrm = 1.f;
#pragma unroll
                for (int ct = 0; ct < 4; ++ct) {
                    int col = wc * 64 + ct * 16 + (l & 15);
                    out[n * DOUT + col] = acc[rt][ct][r] / nrm;
                }
            }
        }
}

// ---------------------------------------------------------------- launcher
extern "C" void kernel_launch(void* const* d_in, const int* in_sizes, int n_in,
                              void* d_out, int out_size, void* d_ws, size_t ws_size,
                              hipStream_t stream) {
    const float* h_node  = (const float*)d_in[0];
    const float* h_ngbrs = (const float*)d_in[1];
    const float* alpha   = (const float*)d_in[2];
    const float* Wq      = (const float*)d_in[3];
    const float* bq      = (const float*)d_in[4];
    const float* Ww      = (const float*)d_in[5];
    const float* bw      = (const float*)d_in[6];
    float* out   = (float*)d_out;
    _Float16* ws = (_Float16*)d_ws;

    convert_weights<<<24, 256, 0, stream>>>(Wq, Ww, ws);
    // 1,600,000 rows / 128 = 12500 tiles (exact, no tail)
    gemm1_agg<<<12500, 256, 0, stream>>>(h_ngbrs, alpha, bq, ws, out);
    // ceil(50000/128) = 391 node tiles
    gemm2_norm<<<391, 256, 0, stream>>>(h_node, bw, ws, out);
}

// Round 2
// 353.278 us; speedup vs baseline: 1.0495x; 1.0495x over previous
//
#include <hip/hip_runtime.h>

#define NNODES 50000
#define DIN 128
#define DHID 128
#define DOUT 128
#define NEG_SLOPE 0.01f

typedef _Float16 f16x8 __attribute__((ext_vector_type(8)));
typedef _Float16 f16x4 __attribute__((ext_vector_type(4)));
typedef float f32x4 __attribute__((ext_vector_type(4)));

// d_ws layout (halves):
//  WqB hi: [ct(8)][g(4)][l(64)][8]   = 16384 halves
//  WqB lo: 16384
//  WwB hi: [ct(8)][g(8)][l(64)][8]   = 32768 halves
//  WwB lo: 32768
#define WS_WQ_HI 0
#define WS_WQ_LO 16384
#define WS_WW_HI 32768
#define WS_WW_LO 65536

// ---------------------------------------------------------------- kernel 0
// Convert weights to fp16 hi/lo fragment slabs.
// Fragment convention (mfma_f32_16x16x32_f16):
//   A: row = l&15, k = (l>>4)*8 + j
//   B: col = l&15, k = (l>>4)*8 + j
//   D: col = l&15, row = (l>>4)*4 + r
__global__ void convert_weights(const float* __restrict__ Wq,
                                const float* __restrict__ Ww,
                                _Float16* __restrict__ ws) {
    int id = blockIdx.x * 256 + threadIdx.x;
    if (id < 2048) {  // Wq slots: B[k][col] = Wq[col][k]
        int s  = id;
        int l  = s & 63;
        int g  = (s >> 6) & 3;
        int ct = s >> 8;
        int col = ct * 16 + (l & 15);
        int k0  = g * 32 + (l >> 4) * 8;
        const float* src = Wq + col * DIN + k0;
        f16x8 vh, vl;
#pragma unroll
        for (int j = 0; j < 8; ++j) {
            float v = src[j];
            _Float16 h = (_Float16)v;
            vh[j] = h;
            vl[j] = (_Float16)(v - (float)h);
        }
        *(f16x8*)(ws + WS_WQ_HI + s * 8) = vh;
        *(f16x8*)(ws + WS_WQ_LO + s * 8) = vl;
    } else if (id < 2048 + 4096) {  // Ww slots: B2[k][o] = Ww[o][k]
        int s  = id - 2048;
        int l  = s & 63;
        int g  = (s >> 6) & 7;
        int ct = s >> 9;
        int col = ct * 16 + (l & 15);
        int k0  = g * 32 + (l >> 4) * 8;
        const float* src = Ww + col * (DIN + DHID) + k0;
        f16x8 vh, vl;
#pragma unroll
        for (int j = 0; j < 8; ++j) {
            float v = src[j];
            _Float16 h = (_Float16)v;
            vh[j] = h;
            vl[j] = (_Float16)(v - (float)h);
        }
        *(f16x8*)(ws + WS_WW_HI + s * 8) = vh;
        *(f16x8*)(ws + WS_WW_LO + s * 8) = vl;
    }
}

// ---------------------------------------------------------------- kernel 1
// GEMM1 + leaky + alpha-weighted mean -> hagg (= d_out).
// LDS-free, barrier-free streaming design:
//   tile 128 rows x 128 cols, 4 waves in 2x2 (wave tile 64x64).
//   A fragments: per-lane dwordx4 loads straight from h_ngbrs (f32),
//     register double-buffered one K-chunk ahead, converted f16 hi/lo in-reg.
//   B fragments: direct loads from pre-converted ws slabs (L2-resident).
//   Epilogue: shfl-only reduction; alpha/bq prefetched to regs at entry.
__global__ __launch_bounds__(256, 2) void gemm1_agg(
    const float* __restrict__ hng,    // [NNODES*32][128]
    const float* __restrict__ alpha,  // [NNODES*32]
    const float* __restrict__ bq,     // [128]
    const _Float16* __restrict__ ws,
    float* __restrict__ hagg)         // [NNODES][128]
{
    const int tid  = threadIdx.x;
    const int l    = tid & 63;
    const int wid  = tid >> 6;
    const int wr   = wid >> 1, wc = wid & 1;
    const long R0  = (long)blockIdx.x * 128;
    const int r16  = l & 15;   // A row within 16 / B col within 16
    const int kg   = l >> 4;   // k-group 0..3 (also D row-group)

    // A base for this lane: row = R0 + wr*64 + rt*16 + r16, k-offset kg*8
    const float* aBase = hng + (R0 + wr * 64 + r16) * DIN + kg * 8;

    // prefetch alpha (node weights for this wave's 64 rows) + bias
    float av[4][4];
#pragma unroll
    for (int rt = 0; rt < 4; ++rt)
#pragma unroll
        for (int r = 0; r < 4; ++r)
            av[rt][r] = alpha[R0 + wr * 64 + rt * 16 + kg * 4 + r];
    float bqv[4];
#pragma unroll
    for (int ct = 0; ct < 4; ++ct)
        bqv[ct] = bq[wc * 64 + ct * 16 + r16];

    const _Float16* wqh = ws + WS_WQ_HI;
    const _Float16* wql = ws + WS_WQ_LO;

    f32x4 acc[4][4];
#pragma unroll
    for (int i = 0; i < 4; ++i)
#pragma unroll
        for (int j = 0; j < 4; ++j) acc[i][j] = (f32x4){0.f, 0.f, 0.f, 0.f};

    f32x4 bufA[4][2], bufB[4][2];

    // prologue: chunk 0 -> bufA
#pragma unroll
    for (int rt = 0; rt < 4; ++rt) {
        const float* p = aBase + rt * 16 * DIN;
        bufA[rt][0] = *(const f32x4*)p;
        bufA[rt][1] = *(const f32x4*)(p + 4);
    }

    auto do_chunk = [&](int c, f32x4 (&cur)[4][2], f32x4 (&nxt)[4][2], bool pf) {
        // prefetch next chunk's A (HBM; lands while this chunk computes)
        if (pf) {
#pragma unroll
            for (int rt = 0; rt < 4; ++rt) {
                const float* p = aBase + rt * 16 * DIN + (c + 1) * 32;
                nxt[rt][0] = *(const f32x4*)p;
                nxt[rt][1] = *(const f32x4*)(p + 4);
            }
        }
        // B fragments for this chunk (L2-hit, coalesced 16B/lane)
        f16x8 bh[4], bl[4];
#pragma unroll
        for (int ct = 0; ct < 4; ++ct) {
            int off = (((wc * 4 + ct) * 4 + c) * 64 + l) * 8;
            bh[ct] = *(const f16x8*)(wqh + off);
            bl[ct] = *(const f16x8*)(wql + off);
        }
        // convert + MFMA, per row-tile (keeps ah/al live range short)
#pragma unroll
        for (int rt = 0; rt < 4; ++rt) {
            f16x8 ah, al;
#pragma unroll
            for (int j = 0; j < 8; ++j) {
                float v = (j < 4) ? cur[rt][0][j] : cur[rt][1][j - 4];
                _Float16 h = (_Float16)v;
                ah[j] = h;
                al[j] = (_Float16)(v - (float)h);
            }
#pragma unroll
            for (int ct = 0; ct < 4; ++ct) {
                acc[rt][ct] = __builtin_amdgcn_mfma_f32_16x16x32_f16(ah, bh[ct], acc[rt][ct], 0, 0, 0);
                acc[rt][ct] = __builtin_amdgcn_mfma_f32_16x16x32_f16(ah, bl[ct], acc[rt][ct], 0, 0, 0);
                acc[rt][ct] = __builtin_amdgcn_mfma_f32_16x16x32_f16(al, bh[ct], acc[rt][ct], 0, 0, 0);
            }
        }
    };

    do_chunk(0, bufA, bufB, true);
    do_chunk(1, bufB, bufA, true);
    do_chunk(2, bufA, bufB, true);
    do_chunk(3, bufB, bufA, false);

    // ---- epilogue: +bq, leaky, *alpha, reduce 32 rows/node, safediv, store
    const int grp = kg;  // l>>4
    float part[2][4] = {{0.f, 0.f, 0.f, 0.f}, {0.f, 0.f, 0.f, 0.f}};
    float apart[2] = {0.f, 0.f};
#pragma unroll
    for (int rt = 0; rt < 4; ++rt) {
        const int nl = rt >> 1;
#pragma unroll
        for (int r = 0; r < 4; ++r) {
            float aw = av[rt][r];
            apart[nl] += aw;
#pragma unroll
            for (int ct = 0; ct < 4; ++ct) {
                float v = acc[rt][ct][r] + bqv[ct];
                v = (v >= 0.f) ? v : NEG_SLOPE * v;
                part[nl][ct] += aw * v;
            }
        }
    }
#pragma unroll
    for (int nl = 0; nl < 2; ++nl) {
        apart[nl] += __shfl_xor(apart[nl], 16);
        apart[nl] += __shfl_xor(apart[nl], 32);
#pragma unroll
        for (int ct = 0; ct < 4; ++ct) {
            part[nl][ct] += __shfl_xor(part[nl][ct], 16);
            part[nl][ct] += __shfl_xor(part[nl][ct], 32);
        }
    }
    if (grp < 2) {  // lanes 0..15 -> node0, 16..31 -> node1 (of wave's pair)
        int nl = grp;
        long node = (long)blockIdx.x * 4 + wr * 2 + nl;
        float den = apart[nl];
        if (den == 0.f) den = 1.f;
#pragma unroll
        for (int ct = 0; ct < 4; ++ct) {
            int col = wc * 64 + ct * 16 + r16;
            hagg[node * DHID + col] = part[nl][ct] / den;
        }
    }
}

// ---------------------------------------------------------------- kernel 2
// GEMM2: out = normalize(leaky(concat(h_node, hagg) @ Ww^T + bw))
// Tile: 128 nodes x 128 out, K=256 in 8 chunks of 32. hagg lives in `out`.
__global__ __launch_bounds__(256, 2) void gemm2_norm(
    const float* __restrict__ hnode,  // [NNODES][128]
    const float* __restrict__ bw,     // [128]
    const _Float16* __restrict__ ws,
    float* __restrict__ out)          // [NNODES][128], holds hagg on entry
{
    __shared__ _Float16 Ahi[8 * 520];
    __shared__ _Float16 Alo[8 * 520];
    __shared__ _Float16 Bhi[8 * 512];
    __shared__ _Float16 Blo[8 * 512];
    __shared__ float bw_s[128];
    __shared__ float nbuf[2][128];

    const int tid = threadIdx.x;
    const int l   = tid & 63;
    const int wid = tid >> 6;
    const int wr  = wid >> 1, wc = wid & 1;
    const long NB = (long)blockIdx.x * 128;

    if (tid < 128) bw_s[tid] = bw[tid];

    f32x4 acc[4][4];
#pragma unroll
    for (int i = 0; i < 4; ++i)
#pragma unroll
        for (int j = 0; j < 4; ++j) acc[i][j] = (f32x4){0.f, 0.f, 0.f, 0.f};

    const _Float16* wwh = ws + WS_WW_HI;
    const _Float16* wwl = ws + WS_WW_LO;

    for (int c = 0; c < 8; ++c) {
        __syncthreads();
        // ---- stage A: 128 nodes x 32 k of concat(h_node, hagg)
#pragma unroll
        for (int p = 0; p < 4; ++p) {
            int rl = p * 32 + (tid >> 3);
            long n = NB + rl;
            if (n > NNODES - 1) n = NNODES - 1;  // tail clamp (stores guarded)
            int kw = (tid & 7) * 4;       // within-chunk k
            int kg = c * 32 + kw;         // global k in 0..255
            const float* g = (kg < 128) ? (hnode + n * DIN + kg)
                                        : (out + n * DHID + (kg - 128));
            f32x4 v = *(const f32x4*)g;
            _Float16 h0 = (_Float16)v[0], h1 = (_Float16)v[1];
            _Float16 h2 = (_Float16)v[2], h3 = (_Float16)v[3];
            f16x4 vh = {h0, h1, h2, h3};
            f16x4 vl = {(_Float16)(v[0] - (float)h0), (_Float16)(v[1] - (float)h1),
                        (_Float16)(v[2] - (float)h2), (_Float16)(v[3] - (float)h3)};
            int lw  = (rl & 15) | (((kw >> 3) & 3) << 4);
            int s   = rl >> 4;
            int off = s * 520 + lw * 8 + (kw & 7);
            *(f16x4*)(Ahi + off) = vh;
            *(f16x4*)(Alo + off) = vl;
        }
        // ---- stage B slabs (g = c)
#pragma unroll
        for (int i = 0; i < 4; ++i) {
            int id = i * 256 + tid;
            int sb = id >> 6;
            int ls = id & 63;
            if (sb < 8) {
                *(f16x8*)(Bhi + sb * 512 + ls * 8) =
                    *(const f16x8*)(wwh + ((sb * 8 + c) * 64 + ls) * 8);
            } else {
                int ct = sb - 8;
                *(f16x8*)(Blo + ct * 512 + ls * 8) =
                    *(const f16x8*)(wwl + ((ct * 8 + c) * 64 + ls) * 8);
            }
        }
        __syncthreads();
        // ---- compute
        f16x8 ah[4], al[4], bh[4], bl[4];
#pragma unroll
        for (int rt = 0; rt < 4; ++rt) {
            int s = wr * 4 + rt;
            ah[rt] = *(const f16x8*)(Ahi + s * 520 + l * 8);
            al[rt] = *(const f16x8*)(Alo + s * 520 + l * 8);
        }
#pragma unroll
        for (int ct = 0; ct < 4; ++ct) {
            int s = wc * 4 + ct;
            bh[ct] = *(const f16x8*)(Bhi + s * 512 + l * 8);
            bl[ct] = *(const f16x8*)(Blo + s * 512 + l * 8);
        }
#pragma unroll
        for (int rt = 0; rt < 4; ++rt)
#pragma unroll
            for (int ct = 0; ct < 4; ++ct) {
                acc[rt][ct] = __builtin_amdgcn_mfma_f32_16x16x32_f16(ah[rt], bh[ct], acc[rt][ct], 0, 0, 0);
                acc[rt][ct] = __builtin_amdgcn_mfma_f32_16x16x32_f16(ah[rt], bl[ct], acc[rt][ct], 0, 0, 0);
                acc[rt][ct] = __builtin_amdgcn_mfma_f32_16x16x32_f16(al[rt], bh[ct], acc[rt][ct], 0, 0, 0);
            }
    }

    // ---- epilogue: +bw, leaky, row L2-norm (128 cols), safediv, store
    const int grp = l >> 4;
#pragma unroll
    for (int rt = 0; rt < 4; ++rt)
#pragma unroll
        for (int ct = 0; ct < 4; ++ct)
#pragma unroll
            for (int r = 0; r < 4; ++r) {
                int col = wc * 64 + ct * 16 + (l & 15);
                float v = acc[rt][ct][r] + bw_s[col];
                acc[rt][ct][r] = (v >= 0.f) ? v : NEG_SLOPE * v;
            }
    float ssq[4][4];
#pragma unroll
    for (int rt = 0; rt < 4; ++rt)
#pragma unroll
        for (int r = 0; r < 4; ++r) {
            float s = 0.f;
#pragma unroll
            for (int ct = 0; ct < 4; ++ct) s += acc[rt][ct][r] * acc[rt][ct][r];
            s += __shfl_xor(s, 1);
            s += __shfl_xor(s, 2);
            s += __shfl_xor(s, 4);
            s += __shfl_xor(s, 8);
            ssq[rt][r] = s;  // sum over this wave's 64 cols
        }
    if ((l & 15) == 0) {
#pragma unroll
        for (int rt = 0; rt < 4; ++rt)
#pragma unroll
            for (int r = 0; r < 4; ++r)
                nbuf[wc][wr * 64 + rt * 16 + grp * 4 + r] = ssq[rt][r];
    }
    __syncthreads();
#pragma unroll
    for (int rt = 0; rt < 4; ++rt)
#pragma unroll
        for (int r = 0; r < 4; ++r) {
            int rowl = wr * 64 + rt * 16 + grp * 4 + r;
            long n = NB + rowl;
            if (n < NNODES) {
                float nrm = sqrtf(nbuf[0][rowl] + nbuf[1][rowl]);
                if (nrm == 0.f) nrm = 1.f;
#pragma unroll
                for (int ct = 0; ct < 4; ++ct) {
                    int col = wc * 64 + ct * 16 + (l & 15);
                    out[n * DOUT + col] = acc[rt][ct][r] / nrm;
                }
            }
        }
}

// ---------------------------------------------------------------- launcher
extern "C" void kernel_launch(void* const* d_in, const int* in_sizes, int n_in,
                              void* d_out, int out_size, void* d_ws, size_t ws_size,
                              hipStream_t stream) {
    const float* h_node  = (const float*)d_in[0];
    const float* h_ngbrs = (const float*)d_in[1];
    const float* alpha   = (const float*)d_in[2];
    const float* Wq      = (const float*)d_in[3];
    const float* bq      = (const float*)d_in[4];
    const float* Ww      = (const float*)d_in[5];
    const float* bw      = (const float*)d_in[6];
    float* out   = (float*)d_out;
    _Float16* ws = (_Float16*)d_ws;

    convert_weights<<<24, 256, 0, stream>>>(Wq, Ww, ws);
    // 1,600,000 rows / 128 = 12500 tiles (exact, no tail)
    gemm1_agg<<<12500, 256, 0, stream>>>(h_ngbrs, alpha, bq, ws, out);
    // ceil(50000/128) = 391 node tiles
    gemm2_norm<<<391, 256, 0, stream>>>(h_node, bw, ws, out);
}

// Round 3
// 293.105 us; speedup vs baseline: 1.2650x; 1.2053x over previous
//
#include <hip/hip_runtime.h>

#define NNODES 50000
#define DIN 128
#define DHID 128
#define DOUT 128
#define NEG_SLOPE 0.01f

typedef _Float16 f16x8 __attribute__((ext_vector_type(8)));
typedef _Float16 f16x4 __attribute__((ext_vector_type(4)));
typedef float f32x4 __attribute__((ext_vector_type(4)));

// d_ws layout (halves):
//  WqB hi: [ct(8)][g(4)][l(64)][8]   = 16384 halves
//  WqB lo: 16384
//  WwB hi: [ct(8)][g(8)][l(64)][8]   = 32768 halves
//  WwB lo: 32768
#define WS_WQ_HI 0
#define WS_WQ_LO 16384
#define WS_WW_HI 32768
#define WS_WW_LO 65536

__device__ __forceinline__ void gload_lds16(const float* g, float* lds) {
    __builtin_amdgcn_global_load_lds(
        (const __attribute__((address_space(1))) void*)g,
        (__attribute__((address_space(3))) void*)lds, 16, 0, 0);
}

// ---------------------------------------------------------------- kernel 0
// Convert weights to fp16 hi/lo fragment slabs.
// Fragment convention (mfma_f32_16x16x32_f16):
//   A: row = l&15, k = (l>>4)*8 + j
//   B: col = l&15, k = (l>>4)*8 + j
//   D: col = l&15, row = (l>>4)*4 + r
__global__ void convert_weights(const float* __restrict__ Wq,
                                const float* __restrict__ Ww,
                                _Float16* __restrict__ ws) {
    int id = blockIdx.x * 256 + threadIdx.x;
    if (id < 2048) {  // Wq slots: B[k][col] = Wq[col][k]
        int s  = id;
        int l  = s & 63;
        int g  = (s >> 6) & 3;
        int ct = s >> 8;
        int col = ct * 16 + (l & 15);
        int k0  = g * 32 + (l >> 4) * 8;
        const float* src = Wq + col * DIN + k0;
        f16x8 vh, vl;
#pragma unroll
        for (int j = 0; j < 8; ++j) {
            float v = src[j];
            _Float16 h = (_Float16)v;
            vh[j] = h;
            vl[j] = (_Float16)(v - (float)h);
        }
        *(f16x8*)(ws + WS_WQ_HI + s * 8) = vh;
        *(f16x8*)(ws + WS_WQ_LO + s * 8) = vl;
    } else if (id < 2048 + 4096) {  // Ww slots: B2[k][o] = Ww[o][k]
        int s  = id - 2048;
        int l  = s & 63;
        int g  = (s >> 6) & 7;
        int ct = s >> 9;
        int col = ct * 16 + (l & 15);
        int k0  = g * 32 + (l >> 4) * 8;
        const float* src = Ww + col * (DIN + DHID) + k0;
        f16x8 vh, vl;
#pragma unroll
        for (int j = 0; j < 8; ++j) {
            float v = src[j];
            _Float16 h = (_Float16)v;
            vh[j] = h;
            vl[j] = (_Float16)(v - (float)h);
        }
        *(f16x8*)(ws + WS_WW_HI + s * 8) = vh;
        *(f16x8*)(ws + WS_WW_LO + s * 8) = vl;
    }
}

// ---------------------------------------------------------------- kernel 1
// GEMM1 + leaky + alpha-weighted mean -> hagg (= d_out).
// Deep-MLP design: ALL 4 K-chunks of A staged into 4 LDS slabs via
// global_load_lds (issued in prologue, 64KB in flight per block), counted
// vmcnt per chunk (never a premature drain), XOR-swizzled LDS (pre-swizzled
// global source, swizzled ds_read), f32->f16 hi/lo convert after LDS read.
// B fragments in registers, triple-buffered, issue-order pinned by
// sched_barrier(0) fences so hand-counted vmcnt values stay valid.
__global__ __launch_bounds__(256, 2) void gemm1_agg(
    const float* __restrict__ hng,    // [NNODES*32][128]
    const float* __restrict__ alpha,  // [NNODES*32]
    const float* __restrict__ bq,     // [128]
    const _Float16* __restrict__ ws,
    float* __restrict__ hagg)         // [NNODES][128]
{
    __shared__ float As[4][4096];  // 4 chunks x (128 rows x 32 floats) = 64KB

    const int tid = threadIdx.x;
    const int l   = tid & 63;
    const int wid = tid >> 6;          // 0..3
    const int wr  = wid >> 1, wc = wid & 1;
    const long R0 = (long)blockIdx.x * 128;
    const int r16 = l & 15;
    const int kg  = l >> 4;

    // staging geometry: instr (wid,i) covers rows (wid*4+i)*8 .. +8
    const int srow = l >> 3;                      // 0..7 within instr
    const int scol = ((l & 7) ^ srow) * 4;        // pre-swizzled src float off

    // ---- prefetch alpha + bias to regs (issued before all staging; their
    // completion is only needed at the epilogue)
    float av[4][4];
#pragma unroll
    for (int rt = 0; rt < 4; ++rt)
#pragma unroll
        for (int r = 0; r < 4; ++r)
            av[rt][r] = alpha[R0 + wr * 64 + rt * 16 + kg * 4 + r];
    float bqv[4];
#pragma unroll
    for (int ct = 0; ct < 4; ++ct)
        bqv[ct] = bq[wc * 64 + ct * 16 + r16];
    __builtin_amdgcn_sched_barrier(0);

    const _Float16* wqh = ws + WS_WQ_HI;
    const _Float16* wql = ws + WS_WQ_LO;

    f32x4 acc[4][4];
#pragma unroll
    for (int i = 0; i < 4; ++i)
#pragma unroll
        for (int j = 0; j < 4; ++j) acc[i][j] = (f32x4){0.f, 0.f, 0.f, 0.f};

#define STAGE(c)                                                              \
    do {                                                                      \
        _Pragma("unroll")                                                     \
        for (int i_ = 0; i_ < 4; ++i_) {                                      \
            const float* g_ = hng + (R0 + (wid * 4 + i_) * 8 + srow) * DIN +  \
                              (c) * 32 + scol;                                \
            gload_lds16(g_, &As[c][(wid * 4 + i_) * 256]);                    \
        }                                                                     \
    } while (0)

#define LOADB(c, BH, BL)                                                      \
    do {                                                                      \
        _Pragma("unroll")                                                     \
        for (int ct_ = 0; ct_ < 4; ++ct_) {                                   \
            int off_ = (((wc * 4 + ct_) * 4 + (c)) * 64 + l) * 8;             \
            BH[ct_] = *(const f16x8*)(wqh + off_);                            \
            BL[ct_] = *(const f16x8*)(wql + off_);                            \
        }                                                                     \
    } while (0)

#define COMPUTE(c, BH, BL)                                                    \
    do {                                                                      \
        _Pragma("unroll")                                                     \
        for (int rt_ = 0; rt_ < 4; ++rt_) {                                   \
            int row_ = wr * 64 + rt_ * 16 + r16;                              \
            int sw_  = (r16 & 7) << 4;                                        \
            const char* rb_ = (const char*)&As[c][row_ * 32];                 \
            f32x4 v0_ = *(const f32x4*)(rb_ + ((kg * 32 + 0) ^ sw_));         \
            f32x4 v1_ = *(const f32x4*)(rb_ + ((kg * 32 + 16) ^ sw_));        \
            f16x8 ah_, al_;                                                   \
            _Pragma("unroll")                                                 \
            for (int j_ = 0; j_ < 4; ++j_) {                                  \
                _Float16 h_ = (_Float16)v0_[j_];                              \
                ah_[j_] = h_;                                                 \
                al_[j_] = (_Float16)(v0_[j_] - (float)h_);                    \
            }                                                                 \
            _Pragma("unroll")                                                 \
            for (int j_ = 0; j_ < 4; ++j_) {                                  \
                _Float16 h_ = (_Float16)v1_[j_];                              \
                ah_[j_ + 4] = h_;                                             \
                al_[j_ + 4] = (_Float16)(v1_[j_] - (float)h_);                \
            }                                                                 \
            _Pragma("unroll")                                                 \
            for (int ct_ = 0; ct_ < 4; ++ct_) {                               \
                acc[rt_][ct_] = __builtin_amdgcn_mfma_f32_16x16x32_f16(       \
                    ah_, BH[ct_], acc[rt_][ct_], 0, 0, 0);                    \
                acc[rt_][ct_] = __builtin_amdgcn_mfma_f32_16x16x32_f16(       \
                    ah_, BL[ct_], acc[rt_][ct_], 0, 0, 0);                    \
                acc[rt_][ct_] = __builtin_amdgcn_mfma_f32_16x16x32_f16(       \
                    al_, BH[ct_], acc[rt_][ct_], 0, 0, 0);                    \
            }                                                                 \
        }                                                                     \
    } while (0)

    f16x8 bh0[4], bl0[4], bh1[4], bl1[4], bh2[4], bl2[4];

    // ---- prologue: issue order pinned by fences; per-wave VMEM queue:
    //  [s0:4][B0:8][s1:4][B1:8][s2:4][s3:4]  = 32 ops
    STAGE(0);
    __builtin_amdgcn_sched_barrier(0);
    LOADB(0, bh0, bl0);
    __builtin_amdgcn_sched_barrier(0);
    STAGE(1);
    __builtin_amdgcn_sched_barrier(0);
    LOADB(1, bh1, bl1);
    __builtin_amdgcn_sched_barrier(0);
    STAGE(2);
    STAGE(3);
    __builtin_amdgcn_sched_barrier(0);

    // ---- iter 0: +B2 -> queue 40; need s0+B0 -> newest 28 may remain
    LOADB(2, bh2, bl2);
    __builtin_amdgcn_sched_barrier(0);
    asm volatile("s_waitcnt vmcnt(28)" ::: "memory");
    __builtin_amdgcn_s_barrier();
    __builtin_amdgcn_sched_barrier(0);
    COMPUTE(0, bh0, bl0);

    // ---- iter 1: +B3 (reuse buf0; B0 dead); need s1+B1 -> newest 24 remain
    LOADB(3, bh0, bl0);
    __builtin_amdgcn_sched_barrier(0);
    asm volatile("s_waitcnt vmcnt(24)" ::: "memory");
    __builtin_amdgcn_s_barrier();
    __builtin_amdgcn_sched_barrier(0);
    COMPUTE(1, bh1, bl1);

    // ---- iter 2: need s2+B2 -> only B3 (8) may remain
    asm volatile("s_waitcnt vmcnt(8)" ::: "memory");
    __builtin_amdgcn_s_barrier();
    __builtin_amdgcn_sched_barrier(0);
    COMPUTE(2, bh2, bl2);

    // ---- iter 3: need s3+B3 -> drain (queue naturally empty after)
    asm volatile("s_waitcnt vmcnt(0)" ::: "memory");
    __builtin_amdgcn_s_barrier();
    __builtin_amdgcn_sched_barrier(0);
    COMPUTE(3, bh0, bl0);

#undef STAGE
#undef LOADB
#undef COMPUTE

    // ---- epilogue: +bq, leaky, *alpha, reduce 32 rows/node, safediv, store
    const int grp = kg;
    float part[2][4] = {{0.f, 0.f, 0.f, 0.f}, {0.f, 0.f, 0.f, 0.f}};
    float apart[2] = {0.f, 0.f};
#pragma unroll
    for (int rt = 0; rt < 4; ++rt) {
        const int nl = rt >> 1;
#pragma unroll
        for (int r = 0; r < 4; ++r) {
            float aw = av[rt][r];
            apart[nl] += aw;
#pragma unroll
            for (int ct = 0; ct < 4; ++ct) {
                float v = acc[rt][ct][r] + bqv[ct];
                v = (v >= 0.f) ? v : NEG_SLOPE * v;
                part[nl][ct] += aw * v;
            }
        }
    }
#pragma unroll
    for (int nl = 0; nl < 2; ++nl) {
        apart[nl] += __shfl_xor(apart[nl], 16);
        apart[nl] += __shfl_xor(apart[nl], 32);
#pragma unroll
        for (int ct = 0; ct < 4; ++ct) {
            part[nl][ct] += __shfl_xor(part[nl][ct], 16);
            part[nl][ct] += __shfl_xor(part[nl][ct], 32);
        }
    }
    if (grp < 2) {  // lanes 0..15 -> node0, 16..31 -> node1 (of wave's pair)
        int nl = grp;
        long node = (long)blockIdx.x * 4 + wr * 2 + nl;
        float den = apart[nl];
        if (den == 0.f) den = 1.f;
#pragma unroll
        for (int ct = 0; ct < 4; ++ct) {
            int col = wc * 64 + ct * 16 + r16;
            hagg[node * DHID + col] = part[nl][ct] / den;
        }
    }
}

// ---------------------------------------------------------------- kernel 2
// GEMM2: out = normalize(leaky(concat(h_node, hagg) @ Ww^T + bw))
// Tile: 128 nodes x 128 out, K=256 in 8 chunks of 32. hagg lives in `out`.
__global__ __launch_bounds__(256, 2) void gemm2_norm(
    const float* __restrict__ hnode,  // [NNODES][128]
    const float* __restrict__ bw,     // [128]
    const _Float16* __restrict__ ws,
    float* __restrict__ out)          // [NNODES][128], holds hagg on entry
{
    __shared__ _Float16 Ahi[8 * 520];
    __shared__ _Float16 Alo[8 * 520];
    __shared__ _Float16 Bhi[8 * 512];
    __shared__ _Float16 Blo[8 * 512];
    __shared__ float bw_s[128];
    __shared__ float nbuf[2][128];

    const int tid = threadIdx.x;
    const int l   = tid & 63;
    const int wid = tid >> 6;
    const int wr  = wid >> 1, wc = wid & 1;
    const long NB = (long)blockIdx.x * 128;

    if (tid < 128) bw_s[tid] = bw[tid];

    f32x4 acc[4][4];
#pragma unroll
    for (int i = 0; i < 4; ++i)
#pragma unroll
        for (int j = 0; j < 4; ++j) acc[i][j] = (f32x4){0.f, 0.f, 0.f, 0.f};

    const _Float16* wwh = ws + WS_WW_HI;
    const _Float16* wwl = ws + WS_WW_LO;

    for (int c = 0; c < 8; ++c) {
        __syncthreads();
        // ---- stage A: 128 nodes x 32 k of concat(h_node, hagg)
#pragma unroll
        for (int p = 0; p < 4; ++p) {
            int rl = p * 32 + (tid >> 3);
            long n = NB + rl;
            if (n > NNODES - 1) n = NNODES - 1;  // tail clamp (stores guarded)
            int kw = (tid & 7) * 4;       // within-chunk k
            int kgl = c * 32 + kw;        // global k in 0..255
            const float* g = (kgl < 128) ? (hnode + n * DIN + kgl)
                                         : (out + n * DHID + (kgl - 128));
            f32x4 v = *(const f32x4*)g;
            _Float16 h0 = (_Float16)v[0], h1 = (_Float16)v[1];
            _Float16 h2 = (_Float16)v[2], h3 = (_Float16)v[3];
            f16x4 vh = {h0, h1, h2, h3};
            f16x4 vl = {(_Float16)(v[0] - (float)h0), (_Float16)(v[1] - (float)h1),
                        (_Float16)(v[2] - (float)h2), (_Float16)(v[3] - (float)h3)};
            int lw  = (rl & 15) | (((kw >> 3) & 3) << 4);
            int s   = rl >> 4;
            int off = s * 520 + lw * 8 + (kw & 7);
            *(f16x4*)(Ahi + off) = vh;
            *(f16x4*)(Alo + off) = vl;
        }
        // ---- stage B slabs (g = c)
#pragma unroll
        for (int i = 0; i < 4; ++i) {
            int id = i * 256 + tid;
            int sb = id >> 6;
            int ls = id & 63;
            if (sb < 8) {
                *(f16x8*)(Bhi + sb * 512 + ls * 8) =
                    *(const f16x8*)(wwh + ((sb * 8 + c) * 64 + ls) * 8);
            } else {
                int ct = sb - 8;
                *(f16x8*)(Blo + ct * 512 + ls * 8) =
                    *(const f16x8*)(wwl + ((ct * 8 + c) * 64 + ls) * 8);
            }
        }
        __syncthreads();
        // ---- compute
        f16x8 ah[4], al[4], bh[4], bl[4];
#pragma unroll
        for (int rt = 0; rt < 4; ++rt) {
            int s = wr * 4 + rt;
            ah[rt] = *(const f16x8*)(Ahi + s * 520 + l * 8);
            al[rt] = *(const f16x8*)(Alo + s * 520 + l * 8);
        }
#pragma unroll
        for (int ct = 0; ct < 4; ++ct) {
            int s = wc * 4 + ct;
            bh[ct] = *(const f16x8*)(Bhi + s * 512 + l * 8);
            bl[ct] = *(const f16x8*)(Blo + s * 512 + l * 8);
        }
#pragma unroll
        for (int rt = 0; rt < 4; ++rt)
#pragma unroll
            for (int ct = 0; ct < 4; ++ct) {
                acc[rt][ct] = __builtin_amdgcn_mfma_f32_16x16x32_f16(ah[rt], bh[ct], acc[rt][ct], 0, 0, 0);
                acc[rt][ct] = __builtin_amdgcn_mfma_f32_16x16x32_f16(ah[rt], bl[ct], acc[rt][ct], 0, 0, 0);
                acc[rt][ct] = __builtin_amdgcn_mfma_f32_16x16x32_f16(al[rt], bh[ct], acc[rt][ct], 0, 0, 0);
            }
    }

    // ---- epilogue: +bw, leaky, row L2-norm (128 cols), safediv, store
    const int grp = l >> 4;
#pragma unroll
    for (int rt = 0; rt < 4; ++rt)
#pragma unroll
        for (int ct = 0; ct < 4; ++ct)
#pragma unroll
            for (int r = 0; r < 4; ++r) {
                int col = wc * 64 + ct * 16 + (l & 15);
                float v = acc[rt][ct][r] + bw_s[col];
                acc[rt][ct][r] = (v >= 0.f) ? v : NEG_SLOPE * v;
            }
    float ssq[4][4];
#pragma unroll
    for (int rt = 0; rt < 4; ++rt)
#pragma unroll
        for (int r = 0; r < 4; ++r) {
            float s = 0.f;
#pragma unroll
            for (int ct = 0; ct < 4; ++ct) s += acc[rt][ct][r] * acc[rt][ct][r];
            s += __shfl_xor(s, 1);
            s += __shfl_xor(s, 2);
            s += __shfl_xor(s, 4);
            s += __shfl_xor(s, 8);
            ssq[rt][r] = s;  // sum over this wave's 64 cols
        }
    if ((l & 15) == 0) {
#pragma unroll
        for (int rt = 0; rt < 4; ++rt)
#pragma unroll
            for (int r = 0; r < 4; ++r)
                nbuf[wc][wr * 64 + rt * 16 + grp * 4 + r] = ssq[rt][r];
    }
    __syncthreads();
#pragma unroll
    for (int rt = 0; rt < 4; ++rt)
#pragma unroll
        for (int r = 0; r < 4; ++r) {
            int rowl = wr * 64 + rt * 16 + grp * 4 + r;
            long n = NB + rowl;
            if (n < NNODES) {
                float nrm = sqrtf(nbuf[0][rowl] + nbuf[1][rowl]);
                if (nrm == 0.f) nrm = 1.f;
#pragma unroll
                for (int ct = 0; ct < 4; ++ct) {
                    int col = wc * 64 + ct * 16 + (l & 15);
                    out[n * DOUT + col] = acc[rt][ct][r] / nrm;
                }
            }
        }
}

// ---------------------------------------------------------------- launcher
extern "C" void kernel_launch(void* const* d_in, const int* in_sizes, int n_in,
                              void* d_out, int out_size, void* d_ws, size_t ws_size,
                              hipStream_t stream) {
    const float* h_node  = (const float*)d_in[0];
    const float* h_ngbrs = (const float*)d_in[1];
    const float* alpha   = (const float*)d_in[2];
    const float* Wq      = (const float*)d_in[3];
    const float* bq      = (const float*)d_in[4];
    const float* Ww      = (const float*)d_in[5];
    const float* bw      = (const float*)d_in[6];
    float* out   = (float*)d_out;
    _Float16* ws = (_Float16*)d_ws;

    convert_weights<<<24, 256, 0, stream>>>(Wq, Ww, ws);
    // 1,600,000 rows / 128 = 12500 tiles (exact, no tail)
    gemm1_agg<<<12500, 256, 0, stream>>>(h_ngbrs, alpha, bq, ws, out);
    // ceil(50000/128) = 391 node tiles
    gemm2_norm<<<391, 256, 0, stream>>>(h_node, bw, ws, out);
}